// Round 4
// baseline (482.040 us; speedup 1.0000x reference)
//
#include <hip/hip_runtime.h>
#include <hip/hip_bf16.h>
#include <cmath>

using bf16 = __hip_bfloat16;
typedef _Float16 f16x8 __attribute__((ext_vector_type(8)));
typedef float f32x16 __attribute__((ext_vector_type(16)));

// Load element i of an EXTERNAL input whose dtype is decided by flag f:
// f=1 -> fp32, f=0 -> bf16. Element-index based so pointer math is dtype-free.
__device__ __forceinline__ float ldin(const void* p, size_t i, int f) {
    return f ? ((const float*)p)[i] : __bfloat162float(((const bf16*)p)[i]);
}

__device__ __forceinline__ float bfu(unsigned short u) {
    union { unsigned u32; float f; } x; x.u32 = (unsigned)u << 16; return x.f;
}

// Rotation swizzle: chunk c (16B, 8 f16 ch) of pixel X lives at slot
// (c + swq(X)) & 3 within the 64B pixel block. Bank-quad = (4X + slot) mod 8
// covers all 8 quads over 8 consecutive X -> conflict-free b128 reads+writes.
__device__ __forceinline__ int swq(int X) { return (X + (X >> 2)) & 3; }

// ---------------- dtype detector: 64 blocks, atomic count into flag[1] ------
// flag[0..1] pre-zeroed by hipMemsetAsync. Consumers use f = (flag[1] > 32).
__global__ void detect_kernel(const unsigned short* __restrict__ u, int* __restrict__ flag) {
    __shared__ int s_bad;
    if (threadIdx.x == 0) s_bad = 0;
    __syncthreads();
    int base = blockIdx.x * 256 + threadIdx.x;
    int bad = 0;
#pragma unroll
    for (int k = 0; k < 4; ++k) {
        unsigned short v = u[2 * (base + k * 16384)];
        int e = (v >> 7) & 0xFF;
        if (e == 0xFF || (e == 0 && (v & 0x7FFF))) bad++;
    }
    if (bad) atomicAdd(&s_bad, bad);
    __syncthreads();
    if (threadIdx.x == 0 && s_bad) atomicAdd(&flag[1], s_bad);
}

// ---------------- weight/BN pack: fold BN scale into f16 MFMA B-fragments ---
// ws layout (bytes):
//   0      flag (8B used)
//   160    wpkN  : f16 [lay4][kc4][t9][lane64][e8]          (147456 B)
//   147616 wpkF  : f16 [kc2][t9][lane64][e8]                (18432 B)
//   166048 upwf  : f32 [128]
//   166560 nbias : f32 [4][32]
//   167072 fbias : f32 [32] (oc>=8 -> 0)
//   167424 X     : f16 NHWC scratch buffer (16777216 B)
__global__ void pack_kernel(const void* __restrict__ nw, const void* __restrict__ ng,
                            const void* __restrict__ nb, const void* __restrict__ nm,
                            const void* __restrict__ nv, const void* __restrict__ fw,
                            const void* __restrict__ fg, const void* __restrict__ fb,
                            const void* __restrict__ fm, const void* __restrict__ fv,
                            const void* __restrict__ upw, const int* __restrict__ flag,
                            char* __restrict__ ws) {
    const int f = flag[1] > 32;
    int i = blockIdx.x * 256 + threadIdx.x;
    _Float16* wpkN = (_Float16*)(ws + 160);
    _Float16* wpkF = (_Float16*)(ws + 147616);
    float* upwf  = (float*)(ws + 166048);
    float* nbias = (float*)(ws + 166560);
    float* fbias = (float*)(ws + 167072);
    if (i < 73728) {
        int e = i & 7, lane = (i >> 3) & 63, rest = i >> 9;      // rest = (lay*4+kc)*9+t
        int t = rest % 9, rest2 = rest / 9;
        int kc = rest2 & 3, lay = rest2 >> 2;
        int oc = lane & 31, ic = kc * 16 + ((lane >> 5) << 3) + e;
        float s = ldin(ng, lay * 32 + oc, f) * rsqrtf(ldin(nv, lay * 32 + oc, f) + 1e-5f);
        float w = ldin(nw, ((size_t)(lay * 32 + oc) * 64 + ic) * 9 + t, f);
        wpkN[i] = (_Float16)(w * s);
    } else if (i < 82944) {
        int j = i - 73728;
        int e = j & 7, lane = (j >> 3) & 63, rest = j >> 9;       // rest = kc*9+t
        int t = rest % 9, kc = rest / 9;
        int oc = lane & 31, ic = kc * 16 + ((lane >> 5) << 3) + e;
        float v = 0.f;
        if (oc < 8) {
            float s = ldin(fg, oc, f) * rsqrtf(ldin(fv, oc, f) + 1e-5f);
            v = ldin(fw, ((size_t)(oc * 32 + ic)) * 9 + t, f) * s;
        }
        wpkF[j] = (_Float16)v;
    } else if (i < 83072) {
        int k = i - 82944;
        upwf[k] = ldin(upw, k, f);
    } else if (i < 83200) {
        int k = i - 83072;
        float s = ldin(ng, k, f) * rsqrtf(ldin(nv, k, f) + 1e-5f);
        nbias[k] = ldin(nb, k, f) - ldin(nm, k, f) * s;
    } else if (i < 83232) {
        int k = i - 83200;
        float v = 0.f;
        if (k < 8) {
            float s = ldin(fg, k, f) * rsqrtf(ldin(fv, k, f) + 1e-5f);
            v = ldin(fb, k, f) - ldin(fm, k, f) * s;
        }
        fbias[k] = v;
    }
}

// Channel-gather stage of one 32-ch NCHW tensor tile (external dtype) into the
// rotated NHWC f16 LDS plane. One job = 8 coalesced scalar loads (consecutive
// lanes -> consecutive gx per channel) + ONE b128 LDS write at the rotated
// slot. Conflict-free: quad=(4X+slot)%8 is a full 8-cover over X mod 8.
__device__ __forceinline__ void stage_nchw_g(char* lds, const void* src,
                                             size_t base_elem, int f, int tid,
                                             int x0g, int y0g) {
    for (int job = tid; job < 1360; job += 256) {   // c(4) major, row(10), X(34)
        int c = job / 340, rest = job - c * 340;
        int row = rest / 34, X = rest - row * 34;
        int gy = y0g - 1 + row, gx = x0g - 1 + X;
        union { _Float16 h[8]; uint4 v; } pk;
        if (gy >= 0 && gy < 128 && gx >= 0 && gx < 128) {
            size_t e0 = base_elem + (size_t)(c * 8) * 16384 + (size_t)gy * 128 + gx;
            if (f) {
#pragma unroll
                for (int j = 0; j < 8; ++j)
                    pk.h[j] = (_Float16)(((const float*)src)[e0 + (size_t)j * 16384]);
            } else {
#pragma unroll
                for (int j = 0; j < 8; ++j)
                    pk.h[j] = (_Float16)bfu(((const unsigned short*)src)[e0 + (size_t)j * 16384]);
            }
        } else {
            pk.v = make_uint4(0u, 0u, 0u, 0u);
        }
        int slot = (c + swq(X)) & 3;
        *(uint4*)(lds + row * 2176 + (X << 6) + (slot << 4)) = pk.v;
    }
}

// Stage NHWC f16 tile (internal scratch): linear b128 LDS writes (q<<4 ==
// row*2176 + 64X + 16*slot), source chunk chosen by the inverse rotation.
__device__ __forceinline__ void stage_nhwc(char* lds, const _Float16* xh, int tid,
                                           int b, int x0g, int y0g) {
    for (int q = tid; q < 1360; q += 256) {         // 340 px * 4 slots
        int p = q >> 2, s = q & 3;
        int row = p / 34, X = p - row * 34;
        int c = (s - swq(X)) & 3;                   // inverse rotation
        int gy = y0g - 1 + row, gx = x0g - 1 + X;
        uint4 v = {0u, 0u, 0u, 0u};
        if (gy >= 0 && gy < 128 && gx >= 0 && gx < 128)
            v = *(const uint4*)(xh + (((size_t)(b * 128 + gy) * 128 + gx) * 32 + c * 8));
        *(uint4*)(lds + (q << 4)) = v;
    }
}

// One plane's worth of MFMA accumulation (2 ic-halves * 9 taps).
__device__ __forceinline__ void conv_plane(const char* lds, const _Float16* wseg,
                                           int lane, int wid, int lh,
                                           f32x16& acc0, f32x16& acc1) {
    const int l31 = lane & 31;
#pragma unroll
    for (int kc = 0; kc < 2; ++kc) {
        f16x8 bfr[9];
#pragma unroll
        for (int t = 0; t < 9; ++t)
            bfr[t] = *(const f16x8*)(wseg + (size_t)((kc * 9 + t) * 64 + lane) * 8);
        const int chunk = (kc << 1) | lh;           // 16B chunk = ic 8*chunk..+7
#pragma unroll
        for (int iy = 0; iy < 4; ++iy) {
            const int rowoff = ((wid << 1) + iy) * 2176;
#pragma unroll
            for (int kx = 0; kx < 3; ++kx) {
                const int X = l31 + kx;
                const int slot = (chunk + swq(X)) & 3;
                const f16x8 a = *(const f16x8*)(lds + rowoff + (X << 6) + (slot << 4));
#pragma unroll
                for (int ky = 0; ky < 3; ++ky) {
                    const int y = iy - ky;
                    if (y == 0)
                        acc0 = __builtin_amdgcn_mfma_f32_32x32x16_f16(a, bfr[ky * 3 + kx], acc0, 0, 0, 0);
                    else if (y == 1)
                        acc1 = __builtin_amdgcn_mfma_f32_32x32x16_f16(a, bfr[ky * 3 + kx], acc1, 0, 0, 0);
                }
            }
        }
    }
}

// ---------------- node conv via MFMA implicit GEMM (plane-sequential) -------
// Block: 32x * 8y output tile, 4 waves (2 rows each). LDS: ONE rotated NHWC
// plane (21.76 KB). launch_bounds(256,3): VGPR cap 170 -> no spill risk.
__global__ __launch_bounds__(256, 3) void node_conv_mfma(
    const void* __restrict__ xprev, int xprev_nchw, int xprev_slice,
    const void* __restrict__ layers, int skip_slice,
    const _Float16* __restrict__ wl, const float* __restrict__ bias,
    const int* __restrict__ flag, _Float16* __restrict__ out) {
    __shared__ char lds[21760];
    const int f = flag[1] > 32;
    const int tid = threadIdx.x;
    const int x0g = blockIdx.x << 5, y0g = blockIdx.y << 3, b = blockIdx.z;
    const int lane = tid & 63, wid = tid >> 6;
    const int l31 = lane & 31, lh = lane >> 5;

    f32x16 acc0, acc1;
#pragma unroll
    for (int r = 0; r < 16; ++r) { acc0[r] = 0.f; acc1[r] = 0.f; }

    // plane 1: xprev (ic 0-31)
    if (xprev_nchw)
        stage_nchw_g(lds, xprev, (size_t)xprev_slice * 8388608 + (size_t)b * 524288,
                     f, tid, x0g, y0g);
    else
        stage_nhwc(lds, (const _Float16*)xprev, tid, b, x0g, y0g);
    __syncthreads();
    conv_plane(lds, wl, lane, wid, lh, acc0, acc1);
    __syncthreads();

    // plane 2: skip layer (ic 32-63), always NCHW external
    stage_nchw_g(lds, layers, (size_t)skip_slice * 8388608 + (size_t)b * 524288,
                 f, tid, x0g, y0g);
    __syncthreads();
    conv_plane(lds, wl + 9216, lane, wid, lh, acc0, acc1);   // kc 2,3 fragment block

    // epilogue: bias + ReLU -> f16 NHWC.  D: col(oc)=lane&31, row(x)=(r&3)+8(r>>2)+4(lane>>5)
    const float bs = bias[l31];
    {
        const int gy = y0g + (wid << 1);
#pragma unroll
        for (int r = 0; r < 16; ++r) {
            const int xr = (r & 3) + ((r >> 2) << 3) + (lh << 2);
            out[((size_t)(b * 128 + gy) * 128 + (x0g + xr)) * 32 + l31] =
                (_Float16)fmaxf(acc0[r] + bs, 0.f);
        }
#pragma unroll
        for (int r = 0; r < 16; ++r) {
            const int xr = (r & 3) + ((r >> 2) << 3) + (lh << 2);
            out[((size_t)(b * 128 + gy + 1) * 128 + (x0g + xr)) * 32 + l31] =
                (_Float16)fmaxf(acc1[r] + bs, 0.f);
        }
    }
}

// ---------------- final conv: 32 -> 8 (oc padded to 32), fast tanh ----------
__device__ __forceinline__ float ftanh(float x) {
    float e = __expf(2.f * x);
    return 1.f - 2.f / (e + 1.f);
}

__global__ __launch_bounds__(256, 3) void final_conv_mfma(
    const _Float16* __restrict__ xin, const _Float16* __restrict__ wf,
    const float* __restrict__ fbias, _Float16* __restrict__ outF) {
    __shared__ char lds[21760];
    const int tid = threadIdx.x;
    const int x0g = blockIdx.x << 5, y0g = blockIdx.y << 3, b = blockIdx.z;
    const int lane = tid & 63, wid = tid >> 6;
    const int l31 = lane & 31, lh = lane >> 5;

    stage_nhwc(lds, xin, tid, b, x0g, y0g);
    __syncthreads();

    f32x16 acc0, acc1;
#pragma unroll
    for (int r = 0; r < 16; ++r) { acc0[r] = 0.f; acc1[r] = 0.f; }
    conv_plane(lds, wf, lane, wid, lh, acc0, acc1);

    const float bs = fbias[l31];
    if (l31 < 8) {
        const int gy = y0g + (wid << 1);
#pragma unroll
        for (int r = 0; r < 16; ++r) {
            const int xr = (r & 3) + ((r >> 2) << 3) + (lh << 2);
            outF[((size_t)(b * 128 + gy) * 128 + (x0g + xr)) * 8 + l31] =
                (_Float16)ftanh(acc0[r] + bs);
        }
#pragma unroll
        for (int r = 0; r < 16; ++r) {
            const int xr = (r & 3) + ((r >> 2) << 3) + (lh << 2);
            outF[((size_t)(b * 128 + gy + 1) * 128 + (x0g + xr)) * 8 + l31] =
                (_Float16)ftanh(acc1[r] + bs);
        }
    }
}

// ---------------- depthwise bilinear x2 upsample + ramps, 2x2 quad/thread ----
__global__ __launch_bounds__(256) void upsample_q(
    const _Float16* __restrict__ F, const float* __restrict__ wf,
    const int* __restrict__ flag, void* __restrict__ out) {
    const int f = flag[1] > 32;
    int i = blockIdx.x * 256 + threadIdx.x;
    int qx = i & 127, qy = (i >> 7) & 127, b = i >> 14;

    f16x8 inb[3][3];
#pragma unroll
    for (int jy = 0; jy < 3; ++jy)
#pragma unroll
        for (int jx = 0; jx < 3; ++jx) {
            int iy = qy - 1 + jy, ix = qx - 1 + jx;
            f16x8 v;
#pragma unroll
            for (int c = 0; c < 8; ++c) v[c] = (_Float16)0.f;
            if (iy >= 0 && iy < 128 && ix >= 0 && ix < 128)
                v = *(const f16x8*)(F + (((size_t)(b * 128 + iy) * 128 + ix) << 3));
            inb[jy][jx] = v;
        }

    float acc[32];                                   // [c][dy][dx], static idx
#pragma unroll
    for (int k = 0; k < 32; ++k) acc[k] = 0.f;
#pragma unroll
    for (int ky = 0; ky < 4; ++ky) {
        const int dy = 1 - (ky & 1), jy = 2 - ((ky + 1) >> 1);
#pragma unroll
        for (int kx = 0; kx < 4; ++kx) {
            const int dx = 1 - (kx & 1), jx = 2 - ((kx + 1) >> 1);
            const f16x8 p = inb[jy][jx];
#pragma unroll
            for (int c = 0; c < 8; ++c)
                acc[c * 4 + dy * 2 + dx] =
                    fmaf((float)p[c], wf[c * 16 + ky * 4 + kx], acc[c * 4 + dy * 2 + dx]);
        }
    }
#pragma unroll
    for (int d = 0; d < 4; ++d) {
        acc[d]     += (float)(2 * qy + (d >> 1)) * (1.0f / 256.0f);  // c0: row ramp
        acc[4 + d] += (float)(2 * qx + (d & 1)) * (1.0f / 256.0f);   // c1: col ramp
    }
#pragma unroll
    for (int c = 0; c < 8; ++c)
#pragma unroll
        for (int dy2 = 0; dy2 < 2; ++dy2) {
            size_t a = ((size_t)(b * 8 + c) * 256 + (qy * 2 + dy2)) * 256 + qx * 2;
            float v0 = acc[c * 4 + dy2 * 2], v1 = acc[c * 4 + dy2 * 2 + 1];
            if (f) {
                *(float2*)((float*)out + a) = make_float2(v0, v1);
            } else {
                union { bf16 h; unsigned short u; } u0, u1;
                u0.h = __float2bfloat16(v0); u1.h = __float2bfloat16(v1);
                ((unsigned*)out)[a >> 1] = (unsigned)u0.u | ((unsigned)u1.u << 16);
            }
        }
}

extern "C" void kernel_launch(void* const* d_in, const int* in_sizes, int n_in,
                              void* d_out, int out_size, void* d_ws, size_t ws_size,
                              hipStream_t stream) {
    const void* layers = d_in[0];   // [5][16][32][128][128]
    const void* node_w = d_in[1];   // [4][32][64][3][3]
    const void* ng     = d_in[2];
    const void* nb     = d_in[3];
    const void* nm     = d_in[4];
    const void* nv     = d_in[5];
    const void* fw     = d_in[6];   // [8][32][3][3]
    const void* fg     = d_in[7];
    const void* fb     = d_in[8];
    const void* fm     = d_in[9];
    const void* fv     = d_in[10];
    const void* upw    = d_in[11];  // [8][1][4][4]

    char* ws = (char*)d_ws;
    int* dflag       = (int*)d_ws;
    _Float16* wpkN   = (_Float16*)(ws + 160);
    _Float16* wpkF   = (_Float16*)(ws + 147616);
    float* upwf      = (float*)(ws + 166048);
    float* nbias     = (float*)(ws + 166560);
    float* fbias     = (float*)(ws + 167072);
    _Float16* X      = (_Float16*)(ws + 167424);   // 16.78 MB NHWC f16 scratch
    _Float16* Y      = (_Float16*)d_out;           // d_out reused as second scratch

    hipMemsetAsync(dflag, 0, 16, stream);          // zero flag area (capturable)
    detect_kernel<<<64, 256, 0, stream>>>((const unsigned short*)layers, dflag);
    pack_kernel<<<326, 256, 0, stream>>>(node_w, ng, nb, nm, nv,
                                         fw, fg, fb, fm, fv, upw, dflag, ws);

    dim3 g(4, 16, 16), blk(256);
    // node1: xprev = layers slice 0 (NCHW), skip = slice 1  -> X (ws)
    node_conv_mfma<<<g, blk, 0, stream>>>(layers, 1, 0, layers, 1,
                                          wpkN, nbias, dflag, X);
    // node2: xprev = X (NHWC f16), skip = slice 2           -> Y (d_out)
    node_conv_mfma<<<g, blk, 0, stream>>>(X, 0, 0, layers, 2,
                                          wpkN + 18432, nbias + 32, dflag, Y);
    // node3                                                  -> X
    node_conv_mfma<<<g, blk, 0, stream>>>(Y, 0, 0, layers, 3,
                                          wpkN + 2 * 18432, nbias + 64, dflag, X);
    // node4                                                  -> Y
    node_conv_mfma<<<g, blk, 0, stream>>>(X, 0, 0, layers, 4,
                                          wpkN + 3 * 18432, nbias + 96, dflag, Y);
    // final: reads Y, writes NHWC8 f16 into X (X3 dead)
    final_conv_mfma<<<g, blk, 0, stream>>>(Y, wpkF, fbias, X);
    // upsample: reads X (ws), writes full d_out (Y dead)
    upsample_q<<<1024, 256, 0, stream>>>(X, upwf, dflag, d_out);
}

// Round 5
// 388.829 us; speedup vs baseline: 1.2397x; 1.2397x over previous
//
#include <hip/hip_runtime.h>
#include <hip/hip_bf16.h>
#include <cmath>

using bf16 = __hip_bfloat16;
typedef _Float16 f16x8 __attribute__((ext_vector_type(8)));
typedef float f32x16 __attribute__((ext_vector_type(16)));

// Load element i of an EXTERNAL input whose dtype is decided by flag f:
// f=1 -> fp32, f=0 -> bf16. Element-index based so pointer math is dtype-free.
__device__ __forceinline__ float ldin(const void* p, size_t i, int f) {
    return f ? ((const float*)p)[i] : __bfloat162float(((const bf16*)p)[i]);
}

__device__ __forceinline__ float bfu(unsigned short u) {
    union { unsigned u32; float f; } x; x.u32 = (unsigned)u << 16; return x.f;
}

// Rotation swizzle: chunk c (16B, 8 f16 ch) of pixel X lives at slot
// (c + swq(X)) & 3 within the 64B pixel block. Bank-quad = (4X + slot) mod 8
// covers all 8 quads over 8 consecutive X -> conflict-free b128 reads+writes.
__device__ __forceinline__ int swq(int X) { return (X + (X >> 2)) & 3; }

// ---------------- per-block dtype detection (inside pack_kernel) ------------
// 4096 samples/block of even-index ushorts over first ~2M elements. fp32 low
// mantissa halves ~uniform -> E[bad]=32, P(0)=e^-32~1e-14. Genuine bf16
// normal data: exponent never 0x00(with mantissa)/0xFF -> bad==0 always.
__device__ __forceinline__ int detect_f(const void* layers_) {
    const unsigned short* u = (const unsigned short*)layers_;
    __shared__ int s_bad;
    if (threadIdx.x == 0) s_bad = 0;
    __syncthreads();
    int bad = 0;
#pragma unroll
    for (int k = 0; k < 16; ++k) {
        unsigned short v = u[2 * ((threadIdx.x * 16 + k) * 257)];
        int e = (v >> 7) & 0xFF;
        bad += (e == 0xFF || (e == 0 && (v & 0x7FFF))) ? 1 : 0;
    }
    if (bad) atomicAdd(&s_bad, bad);
    __syncthreads();
    return s_bad > 0;
}

// ---------------- weight/BN pack: fold BN scale into f16 MFMA B-fragments ---
// ws layout (bytes):
//   0      flag (4B: final f, written by pack, read by all later kernels)
//   160    wpkN  : f16 [lay4][kc4][t9][lane64][e8]          (147456 B)
//   147616 wpkF  : f16 [kc2][t9][lane64][e8]                (18432 B)
//   166048 upwf  : f32 [128]
//   166560 nbias : f32 [4][32]
//   167072 fbias : f32 [32] (oc>=8 -> 0)
//   167424 X     : f16 NHWC scratch buffer (16777216 B)
__global__ void pack_kernel(const void* __restrict__ nw, const void* __restrict__ ng,
                            const void* __restrict__ nb, const void* __restrict__ nm,
                            const void* __restrict__ nv, const void* __restrict__ fw,
                            const void* __restrict__ fg, const void* __restrict__ fb,
                            const void* __restrict__ fm, const void* __restrict__ fv,
                            const void* __restrict__ upw, const void* __restrict__ layers_,
                            char* __restrict__ ws) {
    const int f = detect_f(layers_);
    if (blockIdx.x == 0 && threadIdx.x == 0) *(volatile int*)ws = f;
    int i = blockIdx.x * 256 + threadIdx.x;
    _Float16* wpkN = (_Float16*)(ws + 160);
    _Float16* wpkF = (_Float16*)(ws + 147616);
    float* upwf  = (float*)(ws + 166048);
    float* nbias = (float*)(ws + 166560);
    float* fbias = (float*)(ws + 167072);
    if (i < 73728) {
        int e = i & 7, lane = (i >> 3) & 63, rest = i >> 9;      // rest = (lay*4+kc)*9+t
        int t = rest % 9, rest2 = rest / 9;
        int kc = rest2 & 3, lay = rest2 >> 2;
        int oc = lane & 31, ic = kc * 16 + ((lane >> 5) << 3) + e;
        float s = ldin(ng, lay * 32 + oc, f) * rsqrtf(ldin(nv, lay * 32 + oc, f) + 1e-5f);
        float w = ldin(nw, ((size_t)(lay * 32 + oc) * 64 + ic) * 9 + t, f);
        wpkN[i] = (_Float16)(w * s);
    } else if (i < 82944) {
        int j = i - 73728;
        int e = j & 7, lane = (j >> 3) & 63, rest = j >> 9;       // rest = kc*9+t
        int t = rest % 9, kc = rest / 9;
        int oc = lane & 31, ic = kc * 16 + ((lane >> 5) << 3) + e;
        float v = 0.f;
        if (oc < 8) {
            float s = ldin(fg, oc, f) * rsqrtf(ldin(fv, oc, f) + 1e-5f);
            v = ldin(fw, ((size_t)(oc * 32 + ic)) * 9 + t, f) * s;
        }
        wpkF[j] = (_Float16)v;
    } else if (i < 83072) {
        int k = i - 82944;
        upwf[k] = ldin(upw, k, f);
    } else if (i < 83200) {
        int k = i - 83072;
        float s = ldin(ng, k, f) * rsqrtf(ldin(nv, k, f) + 1e-5f);
        nbias[k] = ldin(nb, k, f) - ldin(nm, k, f) * s;
    } else if (i < 83232) {
        int k = i - 83200;
        float v = 0.f;
        if (k < 8) {
            float s = ldin(fg, k, f) * rsqrtf(ldin(fv, k, f) + 1e-5f);
            v = ldin(fb, k, f) - ldin(fm, k, f) * s;
        }
        fbias[k] = v;
    }
}

// Channel-gather stage of one 32-ch NCHW tensor tile (external dtype) into a
// rotated NHWC f16 LDS plane. Fixed 6-trip unrolled loop (guard only on the
// tail) so the compiler can keep many jobs' loads in flight (MLP), instead of
// a vmcnt(0) round-trip per job.
__device__ __forceinline__ void stage_nchw_g(char* lds, const void* src,
                                             size_t base_elem, int f, int tid,
                                             int x0g, int y0g) {
#pragma unroll
    for (int it = 0; it < 6; ++it) {
        int job = tid + it * 256;
        if (it < 5 || job < 1360) {                 // 1360 = 4c * 10rows * 34X
            int c = job / 340, rest = job - c * 340;
            int row = rest / 34, X = rest - row * 34;
            int gy = y0g - 1 + row, gx = x0g - 1 + X;
            union { _Float16 h[8]; uint4 v; } pk;
            if (gy >= 0 && gy < 128 && gx >= 0 && gx < 128) {
                size_t e0 = base_elem + (size_t)(c * 8) * 16384 + (size_t)gy * 128 + gx;
                if (f) {
#pragma unroll
                    for (int j = 0; j < 8; ++j)
                        pk.h[j] = (_Float16)(((const float*)src)[e0 + (size_t)j * 16384]);
                } else {
#pragma unroll
                    for (int j = 0; j < 8; ++j)
                        pk.h[j] = (_Float16)bfu(((const unsigned short*)src)[e0 + (size_t)j * 16384]);
                }
            } else {
                pk.v = make_uint4(0u, 0u, 0u, 0u);
            }
            int slot = (c + swq(X)) & 3;
            *(uint4*)(lds + row * 2176 + (X << 6) + (slot << 4)) = pk.v;
        }
    }
}

// Stage NHWC f16 tile (internal scratch): linear b128 LDS writes, source chunk
// chosen by the inverse rotation. Fixed 6-trip unrolled loop as above.
__device__ __forceinline__ void stage_nhwc(char* lds, const _Float16* xh, int tid,
                                           int b, int x0g, int y0g) {
#pragma unroll
    for (int it = 0; it < 6; ++it) {
        int q = tid + it * 256;
        if (it < 5 || q < 1360) {                   // 340 px * 4 slots
            int p = q >> 2, s = q & 3;
            int row = p / 34, X = p - row * 34;
            int c = (s - swq(X)) & 3;               // inverse rotation
            int gy = y0g - 1 + row, gx = x0g - 1 + X;
            uint4 v = {0u, 0u, 0u, 0u};
            if (gy >= 0 && gy < 128 && gx >= 0 && gx < 128)
                v = *(const uint4*)(xh + (((size_t)(b * 128 + gy) * 128 + gx) * 32 + c * 8));
            *(uint4*)(lds + (q << 4)) = v;
        }
    }
}

// Both planes' MFMA accumulation: 4 ic-chunks of 16 (kc 0,1 -> plane A at
// lds+0; kc 2,3 -> plane B at lds+21760), 9 taps each.
__device__ __forceinline__ void conv_both(const char* lds, const _Float16* wseg,
                                          int lane, int wid, int lh,
                                          f32x16& acc0, f32x16& acc1) {
    const int l31 = lane & 31;
#pragma unroll
    for (int kc = 0; kc < 4; ++kc) {
        f16x8 bfr[9];
#pragma unroll
        for (int t = 0; t < 9; ++t)
            bfr[t] = *(const f16x8*)(wseg + (size_t)((kc * 9 + t) * 64 + lane) * 8);
        const char* pl = lds + ((kc & 2) ? 21760 : 0);
        const int chunk = ((kc & 1) << 1) | lh;     // 16B chunk = ic 8*chunk..+7
#pragma unroll
        for (int iy = 0; iy < 4; ++iy) {
            const int rowoff = ((wid << 1) + iy) * 2176;
#pragma unroll
            for (int kx = 0; kx < 3; ++kx) {
                const int X = l31 + kx;
                const int slot = (chunk + swq(X)) & 3;
                const f16x8 a = *(const f16x8*)(pl + rowoff + (X << 6) + (slot << 4));
#pragma unroll
                for (int ky = 0; ky < 3; ++ky) {
                    const int y = iy - ky;
                    if (y == 0)
                        acc0 = __builtin_amdgcn_mfma_f32_32x32x16_f16(a, bfr[ky * 3 + kx], acc0, 0, 0, 0);
                    else if (y == 1)
                        acc1 = __builtin_amdgcn_mfma_f32_32x32x16_f16(a, bfr[ky * 3 + kx], acc1, 0, 0, 0);
                }
            }
        }
    }
}

// Single-plane version for the final conv (32 ic, plane at lds+0).
__device__ __forceinline__ void conv_plane(const char* lds, const _Float16* wseg,
                                           int lane, int wid, int lh,
                                           f32x16& acc0, f32x16& acc1) {
    const int l31 = lane & 31;
#pragma unroll
    for (int kc = 0; kc < 2; ++kc) {
        f16x8 bfr[9];
#pragma unroll
        for (int t = 0; t < 9; ++t)
            bfr[t] = *(const f16x8*)(wseg + (size_t)((kc * 9 + t) * 64 + lane) * 8);
        const int chunk = (kc << 1) | lh;
#pragma unroll
        for (int iy = 0; iy < 4; ++iy) {
            const int rowoff = ((wid << 1) + iy) * 2176;
#pragma unroll
            for (int kx = 0; kx < 3; ++kx) {
                const int X = l31 + kx;
                const int slot = (chunk + swq(X)) & 3;
                const f16x8 a = *(const f16x8*)(lds + rowoff + (X << 6) + (slot << 4));
#pragma unroll
                for (int ky = 0; ky < 3; ++ky) {
                    const int y = iy - ky;
                    if (y == 0)
                        acc0 = __builtin_amdgcn_mfma_f32_32x32x16_f16(a, bfr[ky * 3 + kx], acc0, 0, 0, 0);
                    else if (y == 1)
                        acc1 = __builtin_amdgcn_mfma_f32_32x32x16_f16(a, bfr[ky * 3 + kx], acc1, 0, 0, 0);
                }
            }
        }
    }
}

// ---------------- node conv via MFMA implicit GEMM (single-barrier) ---------
// Block: 32x * 8y output tile, 4 waves (2 rows each). Both halo planes staged
// before ONE barrier (deep MLP window), 288 MFMAs, then an LDS-assembled
// epilogue producing fully-contiguous uint4 global stores (kills the 3x write
// amplification seen in rocprof: WRITE 51.2 MB vs 16.8 ideal).
__global__ __launch_bounds__(256, 3) void node_conv_mfma(
    const void* __restrict__ xprev, int xprev_nchw, int xprev_slice,
    const void* __restrict__ layers, int skip_slice,
    const _Float16* __restrict__ wl, const float* __restrict__ bias,
    const int* __restrict__ flag, _Float16* __restrict__ out) {
    __shared__ char lds[43520];                 // planeA 0.., planeB 21760..
    const int f = flag[0];
    const int tid = threadIdx.x;
    const int x0g = blockIdx.x << 5, y0g = blockIdx.y << 3, b = blockIdx.z;
    const int lane = tid & 63, wid = tid >> 6;
    const int l31 = lane & 31, lh = lane >> 5;

    // plane A: xprev (ic 0-31); plane B: skip layer (ic 32-63), NCHW external
    if (xprev_nchw)
        stage_nchw_g(lds, xprev, (size_t)xprev_slice * 8388608 + (size_t)b * 524288,
                     f, tid, x0g, y0g);
    else
        stage_nhwc(lds, (const _Float16*)xprev, tid, b, x0g, y0g);
    stage_nchw_g(lds + 21760, layers, (size_t)skip_slice * 8388608 + (size_t)b * 524288,
                 f, tid, x0g, y0g);
    __syncthreads();

    f32x16 acc0, acc1;
#pragma unroll
    for (int r = 0; r < 16; ++r) { acc0[r] = 0.f; acc1[r] = 0.f; }
    conv_both(lds, wl, lane, wid, lh, acc0, acc1);
    __syncthreads();                             // all reads done; lds reusable

    // epilogue: bias+ReLU -> LDS assembly (pixel stride 80B: half-waves land
    // on disjoint bank halves) -> contiguous uint4 global stores.
    const float bs = bias[l31];
    const int row0 = wid << 1;
#pragma unroll
    for (int r = 0; r < 16; ++r) {
        const int xr = (r & 3) + ((r >> 2) << 3) + (lh << 2);
        *(_Float16*)(lds + (row0 * 32 + xr) * 80 + (l31 << 1)) =
            (_Float16)fmaxf(acc0[r] + bs, 0.f);
        *(_Float16*)(lds + ((row0 + 1) * 32 + xr) * 80 + (l31 << 1)) =
            (_Float16)fmaxf(acc1[r] + bs, 0.f);
    }
    __syncthreads();
    const size_t obase = ((size_t)(b * 128 + y0g) * 128 + x0g) * 32;
#pragma unroll
    for (int it = 0; it < 4; ++it) {
        int g = tid + it * 256;                  // 1024 uint4 chunks
        int prow = g >> 7, inrow = g & 127;      // row 0..7, chunk-in-row 0..127
        uint4 v = *(const uint4*)(lds + (prow * 32 + (inrow >> 2)) * 80 + (inrow & 3) * 16);
        *(uint4*)(out + obase + (size_t)prow * 4096 + inrow * 8) = v;
    }
}

// ---------------- final conv: 32 -> 8 (oc padded to 32), fast tanh ----------
__device__ __forceinline__ float ftanh(float x) {
    float e = __expf(2.f * x);
    return 1.f - 2.f / (e + 1.f);
}

__global__ __launch_bounds__(256, 3) void final_conv_mfma(
    const _Float16* __restrict__ xin, const _Float16* __restrict__ wf,
    const float* __restrict__ fbias, _Float16* __restrict__ outF) {
    __shared__ char lds[21760];
    const int tid = threadIdx.x;
    const int x0g = blockIdx.x << 5, y0g = blockIdx.y << 3, b = blockIdx.z;
    const int lane = tid & 63, wid = tid >> 6;
    const int l31 = lane & 31, lh = lane >> 5;

    stage_nhwc(lds, xin, tid, b, x0g, y0g);
    __syncthreads();

    f32x16 acc0, acc1;
#pragma unroll
    for (int r = 0; r < 16; ++r) { acc0[r] = 0.f; acc1[r] = 0.f; }
    conv_plane(lds, wf, lane, wid, lh, acc0, acc1);
    __syncthreads();

    // epilogue: tanh -> LDS assembly (16B/px) -> contiguous uint4 stores
    const float bs = fbias[l31];
    const int row0 = wid << 1;
    if (l31 < 8) {
#pragma unroll
        for (int r = 0; r < 16; ++r) {
            const int xr = (r & 3) + ((r >> 2) << 3) + (lh << 2);
            *(_Float16*)(lds + (row0 * 32 + xr) * 16 + (l31 << 1)) =
                (_Float16)ftanh(acc0[r] + bs);
            *(_Float16*)(lds + ((row0 + 1) * 32 + xr) * 16 + (l31 << 1)) =
                (_Float16)ftanh(acc1[r] + bs);
        }
    }
    __syncthreads();
    {
        int g = tid;                             // 256 uint4 chunks, 1/thread
        int prow = g >> 5, px = g & 31;
        uint4 v = *(const uint4*)(lds + g * 16);
        *(uint4*)(outF + ((size_t)(b * 128 + y0g + prow) * 128 + x0g + px) * 8) = v;
    }
}

// ---------------- depthwise bilinear x2 upsample + ramps, 2x2 quad/thread ----
__global__ __launch_bounds__(256) void upsample_q(
    const _Float16* __restrict__ F, const float* __restrict__ wf,
    const int* __restrict__ flag, void* __restrict__ out) {
    const int f = flag[0];
    int i = blockIdx.x * 256 + threadIdx.x;
    int qx = i & 127, qy = (i >> 7) & 127, b = i >> 14;

    f16x8 inb[3][3];
#pragma unroll
    for (int jy = 0; jy < 3; ++jy)
#pragma unroll
        for (int jx = 0; jx < 3; ++jx) {
            int iy = qy - 1 + jy, ix = qx - 1 + jx;
            f16x8 v;
#pragma unroll
            for (int c = 0; c < 8; ++c) v[c] = (_Float16)0.f;
            if (iy >= 0 && iy < 128 && ix >= 0 && ix < 128)
                v = *(const f16x8*)(F + (((size_t)(b * 128 + iy) * 128 + ix) << 3));
            inb[jy][jx] = v;
        }

    float acc[32];                                   // [c][dy][dx], static idx
#pragma unroll
    for (int k = 0; k < 32; ++k) acc[k] = 0.f;
#pragma unroll
    for (int ky = 0; ky < 4; ++ky) {
        const int dy = 1 - (ky & 1), jy = 2 - ((ky + 1) >> 1);
#pragma unroll
        for (int kx = 0; kx < 4; ++kx) {
            const int dx = 1 - (kx & 1), jx = 2 - ((kx + 1) >> 1);
            const f16x8 p = inb[jy][jx];
#pragma unroll
            for (int c = 0; c < 8; ++c)
                acc[c * 4 + dy * 2 + dx] =
                    fmaf((float)p[c], wf[c * 16 + ky * 4 + kx], acc[c * 4 + dy * 2 + dx]);
        }
    }
#pragma unroll
    for (int d = 0; d < 4; ++d) {
        acc[d]     += (float)(2 * qy + (d >> 1)) * (1.0f / 256.0f);  // c0: row ramp
        acc[4 + d] += (float)(2 * qx + (d & 1)) * (1.0f / 256.0f);   // c1: col ramp
    }
#pragma unroll
    for (int c = 0; c < 8; ++c)
#pragma unroll
        for (int dy2 = 0; dy2 < 2; ++dy2) {
            size_t a = ((size_t)(b * 8 + c) * 256 + (qy * 2 + dy2)) * 256 + qx * 2;
            float v0 = acc[c * 4 + dy2 * 2], v1 = acc[c * 4 + dy2 * 2 + 1];
            if (f) {
                *(float2*)((float*)out + a) = make_float2(v0, v1);
            } else {
                union { bf16 h; unsigned short u; } u0, u1;
                u0.h = __float2bfloat16(v0); u1.h = __float2bfloat16(v1);
                ((unsigned*)out)[a >> 1] = (unsigned)u0.u | ((unsigned)u1.u << 16);
            }
        }
}

extern "C" void kernel_launch(void* const* d_in, const int* in_sizes, int n_in,
                              void* d_out, int out_size, void* d_ws, size_t ws_size,
                              hipStream_t stream) {
    const void* layers = d_in[0];   // [5][16][32][128][128]
    const void* node_w = d_in[1];   // [4][32][64][3][3]
    const void* ng     = d_in[2];
    const void* nb     = d_in[3];
    const void* nm     = d_in[4];
    const void* nv     = d_in[5];
    const void* fw     = d_in[6];   // [8][32][3][3]
    const void* fg     = d_in[7];
    const void* fb     = d_in[8];
    const void* fm     = d_in[9];
    const void* fv     = d_in[10];
    const void* upw    = d_in[11];  // [8][1][4][4]

    char* ws = (char*)d_ws;
    int* dflag       = (int*)d_ws;
    _Float16* wpkN   = (_Float16*)(ws + 160);
    _Float16* wpkF   = (_Float16*)(ws + 147616);
    float* upwf      = (float*)(ws + 166048);
    float* nbias     = (float*)(ws + 166560);
    float* fbias     = (float*)(ws + 167072);
    _Float16* X      = (_Float16*)(ws + 167424);   // 16.78 MB NHWC f16 scratch
    _Float16* Y      = (_Float16*)d_out;           // d_out reused as second scratch

    // pack detects dtype per-block and publishes flag[0]; all later kernels
    // are stream-ordered after it.
    pack_kernel<<<326, 256, 0, stream>>>(node_w, ng, nb, nm, nv,
                                         fw, fg, fb, fm, fv, upw, layers, ws);

    dim3 g(4, 16, 16), blk(256);
    // node1: xprev = layers slice 0 (NCHW), skip = slice 1  -> X (ws)
    node_conv_mfma<<<g, blk, 0, stream>>>(layers, 1, 0, layers, 1,
                                          wpkN, nbias, dflag, X);
    // node2: xprev = X (NHWC f16), skip = slice 2           -> Y (d_out)
    node_conv_mfma<<<g, blk, 0, stream>>>(X, 0, 0, layers, 2,
                                          wpkN + 18432, nbias + 32, dflag, Y);
    // node3                                                  -> X
    node_conv_mfma<<<g, blk, 0, stream>>>(Y, 0, 0, layers, 3,
                                          wpkN + 2 * 18432, nbias + 64, dflag, X);
    // node4                                                  -> Y
    node_conv_mfma<<<g, blk, 0, stream>>>(X, 0, 0, layers, 4,
                                          wpkN + 3 * 18432, nbias + 96, dflag, Y);
    // final: reads Y, writes NHWC8 f16 into X (X3 dead)
    final_conv_mfma<<<g, blk, 0, stream>>>(Y, wpkF, fbias, X);
    // upsample: reads X (ws), writes full d_out (Y dead)
    upsample_q<<<1024, 256, 0, stream>>>(X, upwf, dflag, d_out);
}